// Round 1
// baseline (3105.233 us; speedup 1.0000x reference)
//
#include <hip/hip_runtime.h>

#define N_ROWS   65536   // 64*32*32
#define N_CODES  1024
#define DIM      256
#define CK       8       // codes per chunk

// One thread per row; z-row resident in registers; codebook via wave-uniform
// (scalar) loads. Score = ||e||^2 - 2*z.e  (||z||^2 constant per row, dropped).
__global__ __launch_bounds__(256, 1)
void vq_argmin_kernel(const float* __restrict__ z,
                      const float* __restrict__ emb,
                      float* __restrict__ out_idx) {
    __shared__ float s_norm[N_CODES];
    const int t = threadIdx.x;

    // Cooperative ||e_c||^2 precompute: 4 codes per thread, 4 KB LDS.
    for (int c = t; c < N_CODES; c += 256) {
        const float* ep = emb + (size_t)c * DIM;
        float a0 = 0.f, a1 = 0.f, a2 = 0.f, a3 = 0.f;
        #pragma unroll
        for (int d = 0; d < DIM; d += 4) {
            a0 += ep[d + 0] * ep[d + 0];
            a1 += ep[d + 1] * ep[d + 1];
            a2 += ep[d + 2] * ep[d + 2];
            a3 += ep[d + 3] * ep[d + 3];
        }
        s_norm[c] = (a0 + a1) + (a2 + a3);
    }
    __syncthreads();

    const int r = blockIdx.x * 256 + t;

    // Load this row's 256 floats into registers (float4 loads).
    float zr[DIM];
    const float4* zp = (const float4*)(z + (size_t)r * DIM);
    #pragma unroll
    for (int i = 0; i < DIM / 4; ++i) {
        float4 v = zp[i];
        zr[4 * i + 0] = v.x;
        zr[4 * i + 1] = v.y;
        zr[4 * i + 2] = v.z;
        zr[4 * i + 3] = v.w;
    }

    float best = 3.4e38f;
    int   bidx = 0;

    for (int c0 = 0; c0 < N_CODES; c0 += CK) {
        // Two sub-accumulators per code: 16 independent FMA chains (ILP)
        // and halved sequential-summation rounding error.
        float acc0[CK], acc1[CK];
        #pragma unroll
        for (int k = 0; k < CK; ++k) { acc0[k] = 0.f; acc1[k] = 0.f; }

        const float* ep = emb + (size_t)c0 * DIM;
        #pragma unroll
        for (int d = 0; d < DIM; d += 2) {
            #pragma unroll
            for (int k = 0; k < CK; ++k) {
                acc0[k] += zr[d + 0] * ep[k * DIM + d + 0];
                acc1[k] += zr[d + 1] * ep[k * DIM + d + 1];
            }
        }

        #pragma unroll
        for (int k = 0; k < CK; ++k) {
            float score = s_norm[c0 + k] - 2.0f * (acc0[k] + acc1[k]);
            if (score < best) { best = score; bidx = c0 + k; }  // strict <: lowest index wins
        }
    }

    out_idx[r] = (float)bidx;   // exact for idx < 2^24
}

// One wave per row: lane i copies float4 #i of the winning code row.
__global__ __launch_bounds__(256)
void vq_gather_kernel(const float* __restrict__ emb,
                      const float* __restrict__ idxf,
                      float* __restrict__ zq) {
    const int tid  = blockIdx.x * 256 + threadIdx.x;
    const int r    = tid >> 6;
    const int lane = tid & 63;
    const int idx  = (int)idxf[r];
    const float4* ep = (const float4*)(emb + (size_t)idx * DIM);
    float4 v = ep[lane];
    ((float4*)(zq + (size_t)r * DIM))[lane] = v;
}

extern "C" void kernel_launch(void* const* d_in, const int* in_sizes, int n_in,
                              void* d_out, int out_size, void* d_ws, size_t ws_size,
                              hipStream_t stream) {
    const float* z   = (const float*)d_in[0];   // (64,32,32,256) fp32
    const float* emb = (const float*)d_in[1];   // (1024,256) fp32

    float* zq   = (float*)d_out;                          // output 0: 16,777,216 floats
    float* idxf = (float*)d_out + (size_t)N_ROWS * DIM;   // output 1: 65,536 floats

    vq_argmin_kernel<<<N_ROWS / 256, 256, 0, stream>>>(z, emb, idxf);
    vq_gather_kernel<<<(N_ROWS * 64) / 256, 256, 0, stream>>>(emb, idxf, zq);
}

// Round 2
// 259.102 us; speedup vs baseline: 11.9846x; 11.9846x over previous
//
#include <hip/hip_runtime.h>

typedef _Float16 half8 __attribute__((ext_vector_type(8)));
typedef _Float16 half4 __attribute__((ext_vector_type(4)));
typedef float   float4v __attribute__((ext_vector_type(4)));

#define N_ROWS  65536   // 64*32*32
#define N_CODES 1024
#define DIM     256
#define BM      128
#define BN      128
#define BK      32
#define LDA     40      // padded LDS stride (halves): 32 + 8 keeps 16B align, breaks pow2
#define NBLK    (N_CODES / BN)   // 8 code-blocks
#define SLOTS   (NBLK * 2)       // 2 col-waves per block -> 16 partial slots/row

// ---- one wave per code: ||e||^2 (fp32) + f16 hi/lo split of emb ----
__global__ __launch_bounds__(64)
void vq_prep(const float* __restrict__ emb, float* __restrict__ e_norm,
             _Float16* __restrict__ e_hi, _Float16* __restrict__ e_lo) {
    const int c = blockIdx.x, lane = threadIdx.x;
    float4v v = ((const float4v*)(emb + (size_t)c * DIM))[lane];
    half4 h, l;
    float ss = 0.f;
    #pragma unroll
    for (int j = 0; j < 4; ++j) {
        float x = v[j];
        ss += x * x;
        _Float16 hh = (_Float16)x;
        h[j] = hh;
        l[j] = (_Float16)(x - (float)hh);
    }
    *(half4*)(e_hi + (size_t)c * DIM + lane * 4) = h;
    *(half4*)(e_lo + (size_t)c * DIM + lane * 4) = l;
    #pragma unroll
    for (int m = 32; m >= 1; m >>= 1) ss += __shfl_xor(ss, m, 64);
    if (lane == 0) e_norm[c] = ss;
}

// ---- 128x128 tile: 3-term f16-split MFMA GEMM + fused per-row argmin ----
__global__ __launch_bounds__(256, 2)
void vq_gemm_argmin(const float* __restrict__ z,
                    const _Float16* __restrict__ e_hi,
                    const _Float16* __restrict__ e_lo,
                    const float* __restrict__ e_norm,
                    float2* __restrict__ partial) {
    __shared__ _Float16 sAh[BM * LDA], sAl[BM * LDA];
    __shared__ _Float16 sBh[BN * LDA], sBl[BN * LDA];
    __shared__ float s_nrm[BN];

    const int t = threadIdx.x;
    const int w = t >> 6, lane = t & 63, quad = lane >> 4, l15 = lane & 15;
    const int mbase = (w & 1) * 64, nbase = (w >> 1) * 64;   // wave's 64x64 sub-tile
    const int srow = t >> 1, shv = t & 1;                    // staging: 2 threads/row
    const size_t zoff = ((size_t)blockIdx.y * BM + srow) * DIM + shv * 16;
    const size_t boff = ((size_t)blockIdx.x * BN + srow) * DIM + shv * 16;

    if (t < BN) s_nrm[t] = e_norm[blockIdx.x * BN + t];

    float4v acc[4][4] = {};

    for (int kk = 0; kk < DIM; kk += BK) {
        // global -> regs (no LDS touch yet)
        const float4v* zp = (const float4v*)(z + zoff + kk);
        float4v a0 = zp[0], a1 = zp[1], a2 = zp[2], a3 = zp[3];
        const half8* bhp = (const half8*)(e_hi + boff + kk);
        const half8* blp = (const half8*)(e_lo + boff + kk);
        half8 b_h0 = bhp[0], b_h1 = bhp[1];
        half8 b_l0 = blp[0], b_l1 = blp[1];

        __syncthreads();   // previous iteration's frag reads complete

        // convert A to hi/lo and stage everything
        float fa[16];
        #pragma unroll
        for (int j = 0; j < 4; ++j) {
            fa[j] = a0[j]; fa[4 + j] = a1[j]; fa[8 + j] = a2[j]; fa[12 + j] = a3[j];
        }
        half8 ah[2], al[2];
        #pragma unroll
        for (int i = 0; i < 2; ++i) {
            #pragma unroll
            for (int j = 0; j < 8; ++j) {
                float x = fa[i * 8 + j];
                _Float16 hh = (_Float16)x;
                ah[i][j] = hh;
                al[i][j] = (_Float16)(x - (float)hh);
            }
        }
        _Float16* pa = sAh + srow * LDA + shv * 16;
        _Float16* pl = sAl + srow * LDA + shv * 16;
        *(half8*)pa = ah[0]; *(half8*)(pa + 8) = ah[1];
        *(half8*)pl = al[0]; *(half8*)(pl + 8) = al[1];
        _Float16* pb = sBh + srow * LDA + shv * 16;
        _Float16* pc = sBl + srow * LDA + shv * 16;
        *(half8*)pb = b_h0; *(half8*)(pb + 8) = b_h1;
        *(half8*)pc = b_l0; *(half8*)(pc + 8) = b_l1;

        __syncthreads();

        // fragment loads (A/B frag: lane holds row/col = lane&15, k = quad*8+j)
        half8 fah[4], fal[4], fbh[4], fbl[4];
        #pragma unroll
        for (int i = 0; i < 4; ++i) {
            int ar = (mbase + i * 16 + l15) * LDA + quad * 8;
            fah[i] = *(const half8*)(sAh + ar);
            fal[i] = *(const half8*)(sAl + ar);
            int br = (nbase + i * 16 + l15) * LDA + quad * 8;
            fbh[i] = *(const half8*)(sBh + br);
            fbl[i] = *(const half8*)(sBl + br);
        }
        #pragma unroll
        for (int mt = 0; mt < 4; ++mt) {
            #pragma unroll
            for (int nt = 0; nt < 4; ++nt) {
                acc[mt][nt] = __builtin_amdgcn_mfma_f32_16x16x32_f16(fah[mt], fbh[nt], acc[mt][nt], 0, 0, 0);
                acc[mt][nt] = __builtin_amdgcn_mfma_f32_16x16x32_f16(fah[mt], fbl[nt], acc[mt][nt], 0, 0, 0);
                acc[mt][nt] = __builtin_amdgcn_mfma_f32_16x16x32_f16(fal[mt], fbh[nt], acc[mt][nt], 0, 0, 0);
            }
        }
    }

    // ---- epilogue: score = ||e||^2 - 2*dot; per-row argmin ----
    // C/D layout: col = lane&15, row = quad*4 + reg  [m89-verified]
    float bs[4][4];
    int   bi[4][4];
    #pragma unroll
    for (int mt = 0; mt < 4; ++mt) {
        #pragma unroll
        for (int nt = 0; nt < 4; ++nt) {
            float nrm = s_nrm[nbase + nt * 16 + l15];
            int colg = blockIdx.x * BN + nbase + nt * 16 + l15;
            #pragma unroll
            for (int r = 0; r < 4; ++r) {
                float s = nrm - 2.0f * acc[mt][nt][r];
                if (nt == 0 || s < bs[mt][r] || (s == bs[mt][r] && colg < bi[mt][r])) {
                    bs[mt][r] = s; bi[mt][r] = colg;
                }
            }
        }
    }
    // reduce across the 16 lanes holding the same row (xor within quad group)
    #pragma unroll
    for (int msk = 1; msk < 16; msk <<= 1) {
        #pragma unroll
        for (int mt = 0; mt < 4; ++mt) {
            #pragma unroll
            for (int r = 0; r < 4; ++r) {
                float s2 = __shfl_xor(bs[mt][r], msk, 64);
                int   i2 = __shfl_xor(bi[mt][r], msk, 64);
                if (s2 < bs[mt][r] || (s2 == bs[mt][r] && i2 < bi[mt][r])) {
                    bs[mt][r] = s2; bi[mt][r] = i2;
                }
            }
        }
    }
    if (l15 == 0) {
        #pragma unroll
        for (int mt = 0; mt < 4; ++mt) {
            #pragma unroll
            for (int r = 0; r < 4; ++r) {
                int rowg = blockIdx.y * BM + mbase + mt * 16 + quad * 4 + r;
                float2 p; p.x = bs[mt][r]; p.y = (float)bi[mt][r];
                partial[(size_t)rowg * SLOTS + blockIdx.x * 2 + (w >> 1)] = p;
            }
        }
    }
}

// ---- final argmin over 16 partial slots per row ----
__global__ __launch_bounds__(256)
void vq_reduce(const float2* __restrict__ partial, float* __restrict__ idxf) {
    const int r = blockIdx.x * 256 + threadIdx.x;
    const float2* p = partial + (size_t)r * SLOTS;
    float bs = p[0].x, bi = p[0].y;
    #pragma unroll
    for (int s = 1; s < SLOTS; ++s) {
        float2 v = p[s];
        if (v.x < bs || (v.x == bs && v.y < bi)) { bs = v.x; bi = v.y; }
    }
    idxf[r] = bi;
}

// ---- one wave per row: lane i copies float4 #i of the winning code row ----
__global__ __launch_bounds__(256)
void vq_gather(const float* __restrict__ emb,
               const float* __restrict__ idxf,
               float* __restrict__ zq) {
    const int tid  = blockIdx.x * 256 + threadIdx.x;
    const int r    = tid >> 6;
    const int lane = tid & 63;
    const int idx  = (int)idxf[r];
    const float4* ep = (const float4*)(emb + (size_t)idx * DIM);
    float4 v = ep[lane];
    ((float4*)(zq + (size_t)r * DIM))[lane] = v;
}

extern "C" void kernel_launch(void* const* d_in, const int* in_sizes, int n_in,
                              void* d_out, int out_size, void* d_ws, size_t ws_size,
                              hipStream_t stream) {
    const float* z   = (const float*)d_in[0];   // (64,32,32,256) fp32
    const float* emb = (const float*)d_in[1];   // (1024,256) fp32

    float* zq   = (float*)d_out;                          // output 0: 16,777,216 f
    float* idxf = zq + (size_t)N_ROWS * DIM;              // output 1: 65,536 f

    // scratch: e_norm (4KB pad) + e_hi/e_lo (1MB) + partials (8MB) = 9.4MB
    const size_t need = 4096 + 2 * (size_t)N_CODES * DIM * sizeof(_Float16)
                      + (size_t)N_ROWS * SLOTS * sizeof(float2);
    char* base = (ws_size >= need) ? (char*)d_ws : (char*)d_out;  // z_q area (64MB) is
                                                                  // overwritten by gather last
    float*    e_norm  = (float*)base;
    _Float16* e_hi    = (_Float16*)(base + 4096);
    _Float16* e_lo    = e_hi + (size_t)N_CODES * DIM;
    float2*   partial = (float2*)(e_lo + (size_t)N_CODES * DIM);

    vq_prep<<<N_CODES, 64, 0, stream>>>(emb, e_norm, e_hi, e_lo);
    vq_gemm_argmin<<<dim3(NBLK, N_ROWS / BM), 256, 0, stream>>>(z, e_hi, e_lo, e_norm, partial);
    vq_reduce<<<N_ROWS / 256, 256, 0, stream>>>(partial, idxf);
    vq_gather<<<(N_ROWS * 64) / 256, 256, 0, stream>>>(emb, idxf, zq);
}

// Round 3
// 233.734 us; speedup vs baseline: 13.2853x; 1.1085x over previous
//
#include <hip/hip_runtime.h>

typedef _Float16 half8  __attribute__((ext_vector_type(8)));
typedef _Float16 half4  __attribute__((ext_vector_type(4)));
typedef float    float4v __attribute__((ext_vector_type(4)));
typedef float    float8v __attribute__((ext_vector_type(8)));

#define N_ROWS  65536   // 64*32*32
#define N_CODES 1024
#define DIM     256
#define BM      128     // rows per block
#define NBLKS   (N_ROWS / BM)   // 512

// ---- prep: one wave per code. ||e||^2 (round-2-identical ordering) and
// hi/lo f16 split written in MFMA B-fragment order:
// frag block b = nt*8 + ks holds 1024 halves: [hi 512][lo 512],
// chunk p = quad*16 + l15 -> code = nt*16+l15, k = ks*32 + quad*8 + j.
__global__ __launch_bounds__(64)
void vq_prep(const float* __restrict__ emb, float* __restrict__ e_norm,
             _Float16* __restrict__ e_frag) {
    const int c = blockIdx.x, lane = threadIdx.x;
    const int l15 = c & 15, nt = c >> 4;
    float4v v = ((const float4v*)(emb + (size_t)c * DIM))[lane];
    half4 h, l;
    float ss = 0.f;
    #pragma unroll
    for (int j = 0; j < 4; ++j) {
        float x = v[j];
        ss += x * x;
        _Float16 hh = (_Float16)x;
        h[j] = hh;
        l[j] = (_Float16)(x - (float)hh);
    }
    // this lane's 4 elements: k = lane*4 .. +3
    const int ks = lane >> 3, q = (lane >> 1) & 3, jb = (lane & 1) * 4;
    _Float16* p = e_frag + ((size_t)(nt * 8 + ks)) * 1024 + (q * 16 + l15) * 8 + jb;
    *(half4*)p = h;
    *(half4*)(p + 512) = l;
    #pragma unroll
    for (int m = 32; m >= 1; m >>= 1) ss += __shfl_xor(ss, m, 64);
    if (lane == 0) e_norm[c] = ss;
}

// ---- main: 512 threads (8 waves), BM=128 rows/block, full K in LDS,
// ONE staging barrier. Wave w handles codes [w*128, w*128+128) in 2 passes
// of 64. B-frags direct from global (L2-resident). Fused argmin + gather.
__global__ __launch_bounds__(512, 2)
void vq_main(const float* __restrict__ z,
             const _Float16* __restrict__ e_frag,
             const float* __restrict__ e_norm,
             const float* __restrict__ emb,
             float* __restrict__ zq,
             float* __restrict__ idxf,
             int fused_gather) {
    __shared__ _Float16 sA[64 * 2 * 512];     // [mt*8+ks][hi|lo][512] = 128 KB
    __shared__ float    s_nrm[N_CODES];       // 4 KB
    __shared__ float2   s_best[BM][17];       // padded: 17.4 KB
    __shared__ int      s_idx[BM];

    const int t = threadIdx.x;
    const int w = t >> 6, lane = t & 63, quad = lane >> 4, l15 = lane & 15;
    const int rowblk = blockIdx.x * BM;

    s_nrm[t] = e_norm[t];
    s_nrm[t + 512] = e_norm[t + 512];

    // ---- stage A: full K, hi/lo f16, fragment order, lane-linear LDS writes.
    // wave w stages ks=w for mt=i: global = 16 rows x 128 B contiguous chunks;
    // LDS write addr = fragbase + lane*16 (conflict-free).
    #pragma unroll
    for (int i = 0; i < 8; ++i) {
        const int mt = i, ks = w;
        const int row = mt * 16 + l15;
        const int col = ks * 32 + quad * 8;
        float8v v = *(const float8v*)(z + (size_t)(rowblk + row) * DIM + col);
        half8 h, lo;
        #pragma unroll
        for (int j = 0; j < 8; ++j) {
            float x = v[j];
            _Float16 hh = (_Float16)x;
            h[j] = hh;
            lo[j] = (_Float16)(x - (float)hh);
        }
        _Float16* p = sA + (size_t)((mt * 8 + ks) * 2) * 512 + lane * 8;
        *(half8*)p = h;
        *(half8*)(p + 512) = lo;
    }
    __syncthreads();   // the only compute barrier

    #pragma unroll
    for (int pass = 0; pass < 2; ++pass) {
        const int ntbase = w * 8 + pass * 4;
        float4v acc[8][4] = {};

        for (int ks = 0; ks < 8; ++ks) {
            half8 bh[4], bl[4];
            #pragma unroll
            for (int nt = 0; nt < 4; ++nt) {
                const _Float16* bp = e_frag + ((size_t)((ntbase + nt) * 8 + ks)) * 1024 + lane * 8;
                bh[nt] = *(const half8*)bp;
                bl[nt] = *(const half8*)(bp + 512);
            }
            #pragma unroll
            for (int mt = 0; mt < 8; ++mt) {
                const _Float16* ap = sA + (size_t)((mt * 8 + ks) * 2) * 512 + lane * 8;
                half8 ah = *(const half8*)ap;
                half8 al = *(const half8*)(ap + 512);
                #pragma unroll
                for (int nt = 0; nt < 4; ++nt) {
                    acc[mt][nt] = __builtin_amdgcn_mfma_f32_16x16x32_f16(ah, bh[nt], acc[mt][nt], 0, 0, 0);
                    acc[mt][nt] = __builtin_amdgcn_mfma_f32_16x16x32_f16(ah, bl[nt], acc[mt][nt], 0, 0, 0);
                    acc[mt][nt] = __builtin_amdgcn_mfma_f32_16x16x32_f16(al, bh[nt], acc[mt][nt], 0, 0, 0);
                }
            }
        }

        // ---- pass epilogue: score = ||e||^2 - 2*dot; per-row argmin.
        // C/D layout: col = lane&15, row = quad*4 + reg.
        float nrm[4]; int cg[4];
        #pragma unroll
        for (int nt = 0; nt < 4; ++nt) {
            cg[nt]  = (ntbase + nt) * 16 + l15;
            nrm[nt] = s_nrm[cg[nt]];
        }
        #pragma unroll
        for (int mt = 0; mt < 8; ++mt) {
            #pragma unroll
            for (int r = 0; r < 4; ++r) {
                float bs = 0.f; int bi = 0;
                #pragma unroll
                for (int nt = 0; nt < 4; ++nt) {
                    float s = nrm[nt] - 2.0f * acc[mt][nt][r];
                    if (nt == 0 || s < bs) { bs = s; bi = cg[nt]; }   // ascending codes: strict < = lowest idx
                }
                #pragma unroll
                for (int m = 1; m < 16; m <<= 1) {   // reduce the 16 l15 lanes (same row)
                    float s2 = __shfl_xor(bs, m, 64);
                    int   i2 = __shfl_xor(bi, m, 64);
                    if (s2 < bs || (s2 == bs && i2 < bi)) { bs = s2; bi = i2; }
                }
                if (l15 == 0) {
                    const int row = mt * 16 + quad * 4 + r;
                    float2 pr; pr.x = bs; pr.y = (float)bi;
                    s_best[row][w * 2 + pass] = pr;
                }
            }
        }
    }
    __syncthreads();

    // ---- block reduce over 16 slots/row; write indices
    if (t < BM) {
        float2 p0 = s_best[t][0];
        float bs = p0.x, bi = p0.y;
        #pragma unroll
        for (int s = 1; s < 16; ++s) {
            float2 pv = s_best[t][s];
            if (pv.x < bs || (pv.x == bs && pv.y < bi)) { bs = pv.x; bi = pv.y; }
        }
        s_idx[t] = (int)bi;
        idxf[rowblk + t] = bi;
    }

    if (!fused_gather) return;
    __syncthreads();

    // ---- fused gather: 4 threads/row, 16 float4 each
    const float4v* emb4 = (const float4v*)emb;
    float4v* zq4 = (float4v*)zq;
    const int rr = t >> 2, cb = t & 3;
    const int code = s_idx[rr];
    #pragma unroll
    for (int i = 0; i < 16; ++i) {
        const int chunk = cb + i * 4;
        zq4[(size_t)(rowblk + rr) * 64 + chunk] = emb4[(size_t)code * 64 + chunk];
    }
}

// ---- fallback gather (only when e_frag had to live in d_out): wave per row
__global__ __launch_bounds__(256)
void vq_gather(const float* __restrict__ emb,
               const float* __restrict__ idxf,
               float* __restrict__ zq) {
    const int tid  = blockIdx.x * 256 + threadIdx.x;
    const int r    = tid >> 6;
    const int lane = tid & 63;
    const int idx  = (int)idxf[r];
    const float4* ep = (const float4*)(emb + (size_t)idx * DIM);
    ((float4*)(zq + (size_t)r * DIM))[lane] = ep[lane];
}

extern "C" void kernel_launch(void* const* d_in, const int* in_sizes, int n_in,
                              void* d_out, int out_size, void* d_ws, size_t ws_size,
                              hipStream_t stream) {
    const float* z   = (const float*)d_in[0];   // (64,32,32,256) fp32
    const float* emb = (const float*)d_in[1];   // (1024,256) fp32

    float* zq   = (float*)d_out;                        // output 0: 16,777,216 f
    float* idxf = zq + (size_t)N_ROWS * DIM;            // output 1: 65,536 f

    // scratch: e_norm (4 KB pad) + e_frag (1 MB)
    const size_t need = 4096 + (size_t)N_CODES * DIM * 2 * sizeof(_Float16);
    const int in_ws = (ws_size >= need);
    char* base = in_ws ? (char*)d_ws : (char*)d_out;    // fallback: zq area; then
                                                        // gather must be a later kernel
    float*    e_norm = (float*)base;
    _Float16* e_frag = (_Float16*)(base + 4096);

    vq_prep<<<N_CODES, 64, 0, stream>>>(emb, e_norm, e_frag);
    vq_main<<<NBLKS, 512, 0, stream>>>(z, e_frag, e_norm, emb, zq, idxf, in_ws);
    if (!in_ws)
        vq_gather<<<(N_ROWS * 64) / 256, 256, 0, stream>>>(emb, idxf, zq);
}